// Round 1
// baseline (551.093 us; speedup 1.0000x reference)
//
#include <hip/hip_runtime.h>

typedef __bf16 bf16x8 __attribute__((ext_vector_type(8)));
typedef __bf16 bf16x4 __attribute__((ext_vector_type(4)));
typedef float  f32x4  __attribute__((ext_vector_type(4)));

#define GAMMA 0.99f

__device__ __forceinline__ void gload_lds16(const void* g, void* l) {
  __builtin_amdgcn_global_load_lds(
      (const __attribute__((address_space(1))) void*)g,
      (__attribute__((address_space(3))) void*)l, 16, 0, 0);
}

// ---------------------------------------------------------------- scan ----
// G[i] = r[i] + gamma*G[i+1]; T = 65536 = 1024 threads * 64 elems
__global__ __launch_bounds__(1024) void scan_kernel(const float* __restrict__ rw,
                                                    float* __restrict__ G) {
  __shared__ float sv[1024];
  const int t = threadIdx.x;
  const float4* rp = (const float4*)(rw + t * 64);
  float4 lv[16];
#pragma unroll
  for (int i = 0; i < 16; ++i) lv[i] = rp[i];
  float loc[64];
#pragma unroll
  for (int i = 0; i < 16; ++i) {
    loc[4 * i + 0] = lv[i].x; loc[4 * i + 1] = lv[i].y;
    loc[4 * i + 2] = lv[i].z; loc[4 * i + 3] = lv[i].w;
  }
  float g = 0.f;
#pragma unroll
  for (int j = 63; j >= 0; --j) { g = loc[j] + GAMMA * g; loc[j] = g; }
  sv[t] = g;
  float W = GAMMA;
#pragma unroll
  for (int i = 0; i < 6; ++i) W *= W;  // gamma^64
  float v = g;
  for (int s = 1; s < 1024; s <<= 1) {
    __syncthreads();
    float o = (t + s < 1024) ? sv[t + s] : 0.f;
    __syncthreads();
    v += W * o;
    sv[t] = v;
    W *= W;
  }
  __syncthreads();
  const float nxt = (t < 1023) ? sv[t + 1] : 0.f;
  float pw = GAMMA;
#pragma unroll
  for (int j = 63; j >= 0; --j) {
    G[t * 64 + j] = loc[j] + pw * nxt;
    pw *= GAMMA;
  }
}

// ------------------------------------------------------------ convert W ----
// W [k=1024][n=1024] f32 row-major  ->  bf16, tiled (nb,kt) of [128 n][32 k],
// within tile: row r=n&127 is 4 x 16B k-chunks, chunk g stored at slot g^((r>>1)&3)
__global__ __launch_bounds__(256) void convert_w(const float* __restrict__ W1,
                                                 const float* __restrict__ W2,
                                                 __bf16* __restrict__ Wt1,
                                                 __bf16* __restrict__ Wt2) {
  const int bx = blockIdx.x;
  const float* W = (bx & 256) ? W2 : W1;
  __bf16* O = (bx & 256) ? Wt2 : Wt1;
  const int tile = bx & 255;
  const int nb = tile >> 5, kt = tile & 31;
  const int t = threadIdx.x;
  __shared__ float s[32][129];
#pragma unroll
  for (int rep = 0; rep < 4; ++rep) {
    int f = rep * 256 + t;
    int k = f >> 5;
    int nq = (f & 31) * 4;
    float4 v = *(const float4*)(W + (size_t)(kt * 32 + k) * 1024 + nb * 128 + nq);
    s[k][nq + 0] = v.x; s[k][nq + 1] = v.y; s[k][nq + 2] = v.z; s[k][nq + 3] = v.w;
  }
  __syncthreads();
#pragma unroll
  for (int rep = 0; rep < 2; ++rep) {
    int o = rep * 256 + t;
    int r = o >> 2, q = o & 3;
    int g = q ^ ((r >> 1) & 3);
    bf16x8 u;
#pragma unroll
    for (int e = 0; e < 8; ++e) u[e] = (__bf16)s[g * 8 + e][r];
    *(bf16x8*)(O + (size_t)(nb * 32 + kt) * 4096 + o * 8) = u;
  }
}

// ---------------------------------------------------------------- GEMM1 ----
// h1 = relu(obs @ W1 + b1); obs fp32 [65536][1024]; Wt1 bf16 tiled/swizzled
// out h1 bf16, tiled (mb,kt2) [128][32] with same row-chunk swizzle
__global__ __launch_bounds__(256) void gemm1(const float* __restrict__ obs,
                                             const __bf16* __restrict__ Wt1,
                                             const float* __restrict__ b1,
                                             __bf16* __restrict__ h1) {
  __shared__ __bf16 Alds[128][40];  // padded: +8 bf16 -> 80B row stride
  __shared__ __bf16 Blds[4096];     // [n=128][32 k] swizzled, linear for gload_lds
  const int t = threadIdx.x;
  const int lane = t & 63;
  const int w = t >> 6;
  const int wm = w >> 1, wn = w & 1;
  const int bid = blockIdx.x;
  const int mb = bid >> 3, nb = bid & 7;
  const int g = lane >> 4;
  const int l15 = lane & 15;

  f32x4 acc[4][4];
  const f32x4 zero = {0.f, 0.f, 0.f, 0.f};
#pragma unroll
  for (int i = 0; i < 4; ++i)
#pragma unroll
    for (int j = 0; j < 4; ++j) acc[i][j] = zero;

  const int arow = t >> 3;          // 0..31
  const int akq = (t & 7) * 4;      // k offset (floats)
  const float* aptr = obs + (size_t)(mb * 128 + arow) * 1024 + akq;
  const char* bsrc = (const char*)Wt1 + (size_t)nb * 32 * 8192 + t * 16;
  char* bdst = (char*)Blds + t * 16;

  float4 av[4];
#pragma unroll
  for (int i = 0; i < 4; ++i) av[i] = *(const float4*)(aptr + (size_t)(32 * i) * 1024);

  for (int kt = 0; kt < 32; ++kt) {
    __syncthreads();
    // stage A (fp32 -> bf16)
#pragma unroll
    for (int i = 0; i < 4; ++i) {
      bf16x4 wv = {(__bf16)av[i].x, (__bf16)av[i].y, (__bf16)av[i].z, (__bf16)av[i].w};
      *(bf16x4*)((char*)Alds + (arow + 32 * i) * 80 + akq * 2) = wv;
    }
    // stage B direct to LDS
    const char* bs = bsrc + (size_t)kt * 8192;
    gload_lds16(bs, bdst);
    gload_lds16(bs + 4096, bdst + 4096);
    // prefetch next A tile (overlaps with MFMA wait)
    if (kt < 31) {
      int k0 = (kt + 1) * 32;
#pragma unroll
      for (int i = 0; i < 4; ++i)
        av[i] = *(const float4*)(aptr + (size_t)(32 * i) * 1024 + k0);
    }
    __syncthreads();

    bf16x8 af[4], bfr[4];
#pragma unroll
    for (int i = 0; i < 4; ++i) {
      int row = wm * 64 + 16 * i + l15;
      af[i] = *(const bf16x8*)((const char*)Alds + row * 80 + g * 16);
    }
#pragma unroll
    for (int j = 0; j < 4; ++j) {
      int n = wn * 64 + 16 * j + l15;
      int q = g ^ ((n >> 1) & 3);
      bfr[j] = *(const bf16x8*)((const char*)Blds + n * 64 + q * 16);
    }
#pragma unroll
    for (int i = 0; i < 4; ++i)
#pragma unroll
      for (int j = 0; j < 4; ++j)
        acc[i][j] = __builtin_amdgcn_mfma_f32_16x16x32_bf16(af[i], bfr[j], acc[i][j], 0, 0, 0);
  }

  // epilogue: relu(acc + b1) -> bf16 into swizzled-tiled h1
  const int mrow_base = mb * 128 + wm * 64;
#pragma unroll
  for (int j = 0; j < 4; ++j) {
    const int c = nb * 128 + wn * 64 + 16 * j + l15;
    const float b1v = b1[c];
    const int kt2 = c >> 5;
    const int g2 = (c >> 3) & 3;
    const int cw = c & 7;
#pragma unroll
    for (int i = 0; i < 4; ++i) {
#pragma unroll
      for (int reg = 0; reg < 4; ++reg) {
        int m = mrow_base + 16 * i + g * 4 + reg;
        float v = acc[i][j][reg] + b1v;
        v = v > 0.f ? v : 0.f;
        int r = m & 127;
        int q2 = g2 ^ ((r >> 1) & 3);
        size_t idx = ((size_t)(m >> 7) * 32 + kt2) * 4096 + r * 32 + q2 * 8 + cw;
        h1[idx] = (__bf16)v;
      }
    }
  }
}

// ---------------------------------------------------------------- GEMM2 ----
// h2 = relu(h1 @ W2 + b2); fused: V[m] += sum_c h2[m][c] * W3[c] (atomic)
__global__ __launch_bounds__(256) void gemm2(const __bf16* __restrict__ h1,
                                             const __bf16* __restrict__ Wt2,
                                             const float* __restrict__ b2,
                                             const float* __restrict__ W3,
                                             float* __restrict__ V) {
  __shared__ __bf16 Alds[4096];
  __shared__ __bf16 Blds[4096];
  const int t = threadIdx.x;
  const int lane = t & 63;
  const int w = t >> 6;
  const int wm = w >> 1, wn = w & 1;
  const int bid = blockIdx.x;
  const int mb = bid >> 3, nb = bid & 7;
  const int g = lane >> 4;
  const int l15 = lane & 15;

  f32x4 acc[4][4];
  const f32x4 zero = {0.f, 0.f, 0.f, 0.f};
#pragma unroll
  for (int i = 0; i < 4; ++i)
#pragma unroll
    for (int j = 0; j < 4; ++j) acc[i][j] = zero;

  const char* asrc = (const char*)h1 + (size_t)mb * 32 * 8192 + t * 16;
  const char* bsrc = (const char*)Wt2 + (size_t)nb * 32 * 8192 + t * 16;
  char* adst = (char*)Alds + t * 16;
  char* bdst = (char*)Blds + t * 16;

  for (int kt = 0; kt < 32; ++kt) {
    __syncthreads();
    const char* as = asrc + (size_t)kt * 8192;
    const char* bs = bsrc + (size_t)kt * 8192;
    gload_lds16(as, adst);
    gload_lds16(as + 4096, adst + 4096);
    gload_lds16(bs, bdst);
    gload_lds16(bs + 4096, bdst + 4096);
    __syncthreads();

    bf16x8 af[4], bfr[4];
#pragma unroll
    for (int i = 0; i < 4; ++i) {
      int row = wm * 64 + 16 * i + l15;
      int q = g ^ ((row >> 1) & 3);
      af[i] = *(const bf16x8*)((const char*)Alds + row * 64 + q * 16);
    }
#pragma unroll
    for (int j = 0; j < 4; ++j) {
      int n = wn * 64 + 16 * j + l15;
      int q = g ^ ((n >> 1) & 3);
      bfr[j] = *(const bf16x8*)((const char*)Blds + n * 64 + q * 16);
    }
#pragma unroll
    for (int i = 0; i < 4; ++i)
#pragma unroll
      for (int j = 0; j < 4; ++j)
        acc[i][j] = __builtin_amdgcn_mfma_f32_16x16x32_bf16(af[i], bfr[j], acc[i][j], 0, 0, 0);
  }

  // epilogue: p[m] = sum_c relu(acc + b2[c]) * W3[c]; reduce 16 lanes; atomicAdd
  float p[4][4];
#pragma unroll
  for (int i = 0; i < 4; ++i)
#pragma unroll
    for (int reg = 0; reg < 4; ++reg) p[i][reg] = 0.f;
#pragma unroll
  for (int j = 0; j < 4; ++j) {
    const int c = nb * 128 + wn * 64 + 16 * j + l15;
    const float b2v = b2[c];
    const float w3v = W3[c];
#pragma unroll
    for (int i = 0; i < 4; ++i)
#pragma unroll
      for (int reg = 0; reg < 4; ++reg) {
        float v = acc[i][j][reg] + b2v;
        v = v > 0.f ? v : 0.f;
        p[i][reg] += v * w3v;
      }
  }
#pragma unroll
  for (int d = 1; d < 16; d <<= 1)
#pragma unroll
    for (int i = 0; i < 4; ++i)
#pragma unroll
      for (int reg = 0; reg < 4; ++reg) p[i][reg] += __shfl_xor(p[i][reg], d, 64);
  if (l15 == 0) {
    const int mbase = mb * 128 + wm * 64;
#pragma unroll
    for (int i = 0; i < 4; ++i)
#pragma unroll
      for (int reg = 0; reg < 4; ++reg)
        atomicAdd(&V[mbase + 16 * i + g * 4 + reg], p[i][reg]);
  }
}

// ---------------------------------------------------------------- final ----
__global__ __launch_bounds__(256) void final_kernel(const float* __restrict__ G,
                                                    const float* __restrict__ V,
                                                    const float* __restrict__ b3,
                                                    float* __restrict__ out) {
  int i = blockIdx.x * 256 + threadIdx.x;
  out[i] = G[i] - (V[i] + b3[0]);
}

extern "C" void kernel_launch(void* const* d_in, const int* in_sizes, int n_in,
                              void* d_out, int out_size, void* d_ws, size_t ws_size,
                              hipStream_t stream) {
  const float* rewards = (const float*)d_in[0];
  const float* obs = (const float*)d_in[1];
  const float* W1 = (const float*)d_in[2];
  const float* b1 = (const float*)d_in[3];
  const float* W2 = (const float*)d_in[4];
  const float* b2 = (const float*)d_in[5];
  const float* W3 = (const float*)d_in[6];
  const float* b3 = (const float*)d_in[7];
  float* out = (float*)d_out;

  char* ws = (char*)d_ws;
  __bf16* Wt1 = (__bf16*)(ws);                          // 2 MiB
  __bf16* Wt2 = (__bf16*)(ws + (2u << 20));             // 2 MiB
  float* V = (float*)(ws + (4u << 20));                 // 256 KiB
  float* G = (float*)(ws + (4u << 20) + (256u << 10));  // 256 KiB
  __bf16* h1 = (__bf16*)(ws + (8u << 20));              // 128 MiB

  hipMemsetAsync(V, 0, 65536 * sizeof(float), stream);
  scan_kernel<<<1, 1024, 0, stream>>>(rewards, G);
  convert_w<<<512, 256, 0, stream>>>(W1, W2, Wt1, Wt2);
  gemm1<<<4096, 256, 0, stream>>>(obs, Wt1, b1, h1);
  gemm2<<<4096, 256, 0, stream>>>(h1, Wt2, b2, W3, V);
  final_kernel<<<256, 256, 0, stream>>>(G, V, b3, out);
}

// Round 2
// 507.810 us; speedup vs baseline: 1.0852x; 1.0852x over previous
//
#include <hip/hip_runtime.h>

typedef __bf16 bf16x8 __attribute__((ext_vector_type(8)));
typedef __bf16 bf16x4 __attribute__((ext_vector_type(4)));
typedef float  f32x4  __attribute__((ext_vector_type(4)));

#define GAMMA 0.99f

__device__ __forceinline__ void gload_lds16(const void* g, void* l) {
  __builtin_amdgcn_global_load_lds(
      (const __attribute__((address_space(1))) void*)g,
      (__attribute__((address_space(3))) void*)l, 16, 0, 0);
}

// ---------------------------------------------------------------- scan ----
// G[i] = r[i] + gamma*G[i+1]; T = 65536 = 1024 threads * 64 elems
__global__ __launch_bounds__(1024) void scan_kernel(const float* __restrict__ rw,
                                                    float* __restrict__ G) {
  __shared__ float sv[1024];
  const int t = threadIdx.x;
  const float4* rp = (const float4*)(rw + t * 64);
  float4 lv[16];
#pragma unroll
  for (int i = 0; i < 16; ++i) lv[i] = rp[i];
  float loc[64];
#pragma unroll
  for (int i = 0; i < 16; ++i) {
    loc[4 * i + 0] = lv[i].x; loc[4 * i + 1] = lv[i].y;
    loc[4 * i + 2] = lv[i].z; loc[4 * i + 3] = lv[i].w;
  }
  float g = 0.f;
#pragma unroll
  for (int j = 63; j >= 0; --j) { g = loc[j] + GAMMA * g; loc[j] = g; }
  sv[t] = g;
  float W = GAMMA;
#pragma unroll
  for (int i = 0; i < 6; ++i) W *= W;  // gamma^64
  float v = g;
  for (int s = 1; s < 1024; s <<= 1) {
    __syncthreads();
    float o = (t + s < 1024) ? sv[t + s] : 0.f;
    __syncthreads();
    v += W * o;
    sv[t] = v;
    W *= W;
  }
  __syncthreads();
  const float nxt = (t < 1023) ? sv[t + 1] : 0.f;
  float pw = GAMMA;
#pragma unroll
  for (int j = 63; j >= 0; --j) {
    G[t * 64 + j] = loc[j] + pw * nxt;
    pw *= GAMMA;
  }
}

// ------------------------------------------------------------ convert W ----
// W [k=1024][n=1024] f32 row-major  ->  bf16, tiled (nb,kt) of [128 n][32 k],
// within tile: row r=n&127 is 4 x 16B k-chunks, chunk g stored at slot g^((r>>1)&3)
__global__ __launch_bounds__(256) void convert_w(const float* __restrict__ W1,
                                                 const float* __restrict__ W2,
                                                 __bf16* __restrict__ Wt1,
                                                 __bf16* __restrict__ Wt2) {
  const int bx = blockIdx.x;
  const float* W = (bx & 256) ? W2 : W1;
  __bf16* O = (bx & 256) ? Wt2 : Wt1;
  const int tile = bx & 255;
  const int nb = tile >> 5, kt = tile & 31;
  const int t = threadIdx.x;
  __shared__ float s[32][129];
#pragma unroll
  for (int rep = 0; rep < 4; ++rep) {
    int f = rep * 256 + t;
    int k = f >> 5;
    int nq = (f & 31) * 4;
    float4 v = *(const float4*)(W + (size_t)(kt * 32 + k) * 1024 + nb * 128 + nq);
    s[k][nq + 0] = v.x; s[k][nq + 1] = v.y; s[k][nq + 2] = v.z; s[k][nq + 3] = v.w;
  }
  __syncthreads();
#pragma unroll
  for (int rep = 0; rep < 2; ++rep) {
    int o = rep * 256 + t;
    int r = o >> 2, q = o & 3;
    int g = q ^ ((r >> 1) & 3);
    bf16x8 u;
#pragma unroll
    for (int e = 0; e < 8; ++e) u[e] = (__bf16)s[g * 8 + e][r];
    *(bf16x8*)(O + (size_t)(nb * 32 + kt) * 4096 + o * 8) = u;
  }
}

// ---------------------------------------------------------------- GEMM1 ----
// h1 = relu(obs @ W1 + b1); wide-N: BM=64, BN=1024, BK=32. Grid = 1024 (row
// stripes of 64). obs (fp32) is read EXACTLY ONCE from HBM. Wt1 is L2-resident.
// 8 waves; wave w owns rows 0..63 x cols [w*128, w*128+128).
__global__ __launch_bounds__(512) void gemm1(const float* __restrict__ obs,
                                             const __bf16* __restrict__ Wt1,
                                             const float* __restrict__ b1,
                                             __bf16* __restrict__ h1) {
  __shared__ __bf16 Alds[64 * 32];       // 4 KB, chunk-swizzled
  __shared__ __bf16 Blds[8 * 128 * 32];  // 64 KB: 8 sub-tiles of [128 n][32 k]
  const int t = threadIdx.x;
  const int lane = t & 63;
  const int w = t >> 6;  // wave id = n sub-block
  const int g = lane >> 4;
  const int l15 = lane & 15;
  const int bid = blockIdx.x;  // row stripe: rows bid*64 .. +64

  f32x4 acc[4][8];
  const f32x4 zero = {0.f, 0.f, 0.f, 0.f};
#pragma unroll
  for (int i = 0; i < 4; ++i)
#pragma unroll
    for (int j = 0; j < 8; ++j) acc[i][j] = zero;

  // A: thread loads float4 (row ar, cols ac..ac+3), converts, swizzled ds_write
  const int ar = t >> 3;        // 0..63
  const int ac = (t & 7) * 4;   // 0..28
  const float* aptr = obs + (size_t)(bid * 64 + ar) * 1024 + ac;
  const int ach = ac >> 3;                 // 8-col chunk 0..3
  const int ah = (ac >> 2) & 1;            // half of chunk
  const int aq = ach ^ ((ar >> 1) & 3);    // swizzled slot
  __bf16* adst = Alds + ar * 32 + aq * 8 + ah * 4;

  const char* bsrc = (const char*)Wt1 + t * 16;
  char* bdst = (char*)Blds + t * 16;

  float4 av = *(const float4*)aptr;  // prefetch kt = 0

  for (int kt = 0; kt < 32; ++kt) {
    __syncthreads();
    // stage A (fp32 -> bf16)
    bf16x4 wv = {(__bf16)av.x, (__bf16)av.y, (__bf16)av.z, (__bf16)av.w};
    *(bf16x4*)adst = wv;
    // stage B: 8 sub-tiles, 64 KB, direct to LDS
    const char* bs = bsrc + (size_t)kt * 8192;
#pragma unroll
    for (int s = 0; s < 8; ++s) gload_lds16(bs + s * 262144, bdst + s * 8192);
    // prefetch next A
    if (kt < 31) av = *(const float4*)(aptr + (kt + 1) * 32);
    __syncthreads();

    bf16x8 af[4], bfr[8];
#pragma unroll
    for (int i = 0; i < 4; ++i) {
      int row = 16 * i + l15;
      int q = g ^ ((row >> 1) & 3);
      af[i] = *(const bf16x8*)(Alds + row * 32 + q * 8);
    }
#pragma unroll
    for (int j = 0; j < 8; ++j) {
      int nn = 16 * j + l15;  // col within this wave's sub-tile
      int q = g ^ ((nn >> 1) & 3);
      bfr[j] = *(const bf16x8*)(Blds + w * 4096 + nn * 32 + q * 8);
    }
#pragma unroll
    for (int i = 0; i < 4; ++i)
#pragma unroll
      for (int j = 0; j < 8; ++j)
        acc[i][j] = __builtin_amdgcn_mfma_f32_16x16x32_bf16(af[i], bfr[j], acc[i][j], 0, 0, 0);
  }

  // epilogue: relu(acc + b1) -> bf16 into swizzled-tiled h1 [mbt][kt2][128][32]
  const int mbase = bid * 64;
#pragma unroll
  for (int j = 0; j < 8; ++j) {
    const int c = w * 128 + 16 * j + l15;
    const float b1v = b1[c];
    const int kt2 = c >> 5;
    const int g2 = (c >> 3) & 3;
    const int cw = c & 7;
#pragma unroll
    for (int i = 0; i < 4; ++i) {
#pragma unroll
      for (int reg = 0; reg < 4; ++reg) {
        int m = mbase + 16 * i + g * 4 + reg;
        float v = acc[i][j][reg] + b1v;
        v = v > 0.f ? v : 0.f;
        int r = m & 127;
        int q2 = g2 ^ ((r >> 1) & 3);
        h1[((size_t)(m >> 7) * 32 + kt2) * 4096 + r * 32 + q2 * 8 + cw] = (__bf16)v;
      }
    }
  }
}

// ---------------------------------------------------------------- GEMM2 ----
// h2 = relu(h1 @ W2 + b2), fused V[m] = sum_c h2[m][c]*W3[c].
// Same wide-N structure; h1 read EXACTLY ONCE. Block owns rows exclusively ->
// cross-wave reduce in LDS, plain store to V (no atomics, no memset).
__global__ __launch_bounds__(512) void gemm2(const __bf16* __restrict__ h1,
                                             const __bf16* __restrict__ Wt2,
                                             const float* __restrict__ b2,
                                             const float* __restrict__ W3,
                                             float* __restrict__ V) {
  __shared__ __bf16 Alds[64 * 32];       // 4 KB (verbatim swizzled tile half)
  __shared__ __bf16 Blds[8 * 128 * 32];  // 64 KB
  __shared__ float Vpart[8][64];         // 2 KB
  const int t = threadIdx.x;
  const int lane = t & 63;
  const int w = t >> 6;
  const int g = lane >> 4;
  const int l15 = lane & 15;
  const int bid = blockIdx.x;
  const int mbt = bid >> 1;           // 128-row tile index of h1
  const int r0 = (bid & 1) * 64;      // which half of the tile

  f32x4 acc[4][8];
  const f32x4 zero = {0.f, 0.f, 0.f, 0.f};
#pragma unroll
  for (int i = 0; i < 4; ++i)
#pragma unroll
    for (int j = 0; j < 8; ++j) acc[i][j] = zero;

  // A: verbatim 4 KB copy of half a swizzled h1 tile (swizzle preserved;
  // (r>>1)&3 is invariant under r += 64)
  const char* asrc = (const char*)h1 + (size_t)mbt * 32 * 8192 + r0 * 64 + t * 16;
  char* adst0 = (char*)Alds + t * 16;  // only t<256 valid (4KB)
  const char* bsrc = (const char*)Wt2 + t * 16;
  char* bdst = (char*)Blds + t * 16;

  for (int kt = 0; kt < 32; ++kt) {
    __syncthreads();
    if (t < 256) gload_lds16(asrc + (size_t)kt * 8192, adst0);
    const char* bs = bsrc + (size_t)kt * 8192;
#pragma unroll
    for (int s = 0; s < 8; ++s) gload_lds16(bs + s * 262144, bdst + s * 8192);
    __syncthreads();

    bf16x8 af[4], bfr[8];
#pragma unroll
    for (int i = 0; i < 4; ++i) {
      int row = 16 * i + l15;
      int q = g ^ ((row >> 1) & 3);
      af[i] = *(const bf16x8*)(Alds + row * 32 + q * 8);
    }
#pragma unroll
    for (int j = 0; j < 8; ++j) {
      int nn = 16 * j + l15;
      int q = g ^ ((nn >> 1) & 3);
      bfr[j] = *(const bf16x8*)(Blds + w * 4096 + nn * 32 + q * 8);
    }
#pragma unroll
    for (int i = 0; i < 4; ++i)
#pragma unroll
      for (int j = 0; j < 8; ++j)
        acc[i][j] = __builtin_amdgcn_mfma_f32_16x16x32_bf16(af[i], bfr[j], acc[i][j], 0, 0, 0);
  }

  // epilogue: p = sum over this wave's 128 cols of relu(acc+b2)*W3
  float p[4][4];
#pragma unroll
  for (int i = 0; i < 4; ++i)
#pragma unroll
    for (int reg = 0; reg < 4; ++reg) p[i][reg] = 0.f;
#pragma unroll
  for (int j = 0; j < 8; ++j) {
    const int c = w * 128 + 16 * j + l15;
    const float b2v = b2[c];
    const float w3v = W3[c];
#pragma unroll
    for (int i = 0; i < 4; ++i)
#pragma unroll
      for (int reg = 0; reg < 4; ++reg) {
        float v = acc[i][j][reg] + b2v;
        v = v > 0.f ? v : 0.f;
        p[i][reg] += v * w3v;
      }
  }
#pragma unroll
  for (int d = 1; d < 16; d <<= 1)
#pragma unroll
    for (int i = 0; i < 4; ++i)
#pragma unroll
      for (int reg = 0; reg < 4; ++reg) p[i][reg] += __shfl_xor(p[i][reg], d, 64);
  if (l15 == 0) {
#pragma unroll
    for (int i = 0; i < 4; ++i)
#pragma unroll
      for (int reg = 0; reg < 4; ++reg)
        Vpart[w][16 * i + g * 4 + reg] = p[i][reg];
  }
  __syncthreads();
  if (t < 64) {
    float s = 0.f;
#pragma unroll
    for (int ww = 0; ww < 8; ++ww) s += Vpart[ww][t];
    V[bid * 64 + t] = s;
  }
}

// ---------------------------------------------------------------- final ----
__global__ __launch_bounds__(256) void final_kernel(const float* __restrict__ G,
                                                    const float* __restrict__ V,
                                                    const float* __restrict__ b3,
                                                    float* __restrict__ out) {
  int i = blockIdx.x * 256 + threadIdx.x;
  out[i] = G[i] - (V[i] + b3[0]);
}

extern "C" void kernel_launch(void* const* d_in, const int* in_sizes, int n_in,
                              void* d_out, int out_size, void* d_ws, size_t ws_size,
                              hipStream_t stream) {
  const float* rewards = (const float*)d_in[0];
  const float* obs = (const float*)d_in[1];
  const float* W1 = (const float*)d_in[2];
  const float* b1 = (const float*)d_in[3];
  const float* W2 = (const float*)d_in[4];
  const float* b2 = (const float*)d_in[5];
  const float* W3 = (const float*)d_in[6];
  const float* b3 = (const float*)d_in[7];
  float* out = (float*)d_out;

  char* ws = (char*)d_ws;
  __bf16* Wt1 = (__bf16*)(ws);                          // 2 MiB
  __bf16* Wt2 = (__bf16*)(ws + (2u << 20));             // 2 MiB
  float* V = (float*)(ws + (4u << 20));                 // 256 KiB
  float* G = (float*)(ws + (4u << 20) + (256u << 10));  // 256 KiB
  __bf16* h1 = (__bf16*)(ws + (8u << 20));              // 128 MiB

  scan_kernel<<<1, 1024, 0, stream>>>(rewards, G);
  convert_w<<<512, 256, 0, stream>>>(W1, W2, Wt1, Wt2);
  gemm1<<<1024, 512, 0, stream>>>(obs, Wt1, b1, h1);
  gemm2<<<1024, 512, 0, stream>>>(h1, Wt2, b2, W3, V);
  final_kernel<<<256, 256, 0, stream>>>(G, V, b3, out);
}

// Round 3
// 440.962 us; speedup vs baseline: 1.2498x; 1.1516x over previous
//
#include <hip/hip_runtime.h>

typedef __bf16 bf16x8 __attribute__((ext_vector_type(8)));
typedef __bf16 bf16x4 __attribute__((ext_vector_type(4)));
typedef float  f32x4  __attribute__((ext_vector_type(4)));

#define GAMMA 0.99f

__device__ __forceinline__ void gload_lds16(const void* g, void* l) {
  __builtin_amdgcn_global_load_lds(
      (const __attribute__((address_space(1))) void*)g,
      (__attribute__((address_space(3))) void*)l, 16, 0, 0);
}

#define VMCNT(n) asm volatile("s_waitcnt vmcnt(" #n ")" ::: "memory")
#define LGKM0()                                         \
  do {                                                  \
    asm volatile("s_waitcnt lgkmcnt(0)" ::: "memory");  \
    __builtin_amdgcn_sched_barrier(0);                  \
  } while (0)
#define BAR() __builtin_amdgcn_s_barrier()
#define MFMA(d, a, b) d = __builtin_amdgcn_mfma_f32_16x16x32_bf16(a, b, d, 0, 0, 0)

// ---------------------------------------------------------------- scan ----
__global__ __launch_bounds__(1024) void scan_kernel(const float* __restrict__ rw,
                                                    float* __restrict__ G) {
  __shared__ float sv[1024];
  const int t = threadIdx.x;
  const float4* rp = (const float4*)(rw + t * 64);
  float4 lv[16];
#pragma unroll
  for (int i = 0; i < 16; ++i) lv[i] = rp[i];
  float loc[64];
#pragma unroll
  for (int i = 0; i < 16; ++i) {
    loc[4 * i + 0] = lv[i].x; loc[4 * i + 1] = lv[i].y;
    loc[4 * i + 2] = lv[i].z; loc[4 * i + 3] = lv[i].w;
  }
  float g = 0.f;
#pragma unroll
  for (int j = 63; j >= 0; --j) { g = loc[j] + GAMMA * g; loc[j] = g; }
  sv[t] = g;
  float W = GAMMA;
#pragma unroll
  for (int i = 0; i < 6; ++i) W *= W;  // gamma^64
  float v = g;
  for (int s = 1; s < 1024; s <<= 1) {
    __syncthreads();
    float o = (t + s < 1024) ? sv[t + s] : 0.f;
    __syncthreads();
    v += W * o;
    sv[t] = v;
    W *= W;
  }
  __syncthreads();
  const float nxt = (t < 1023) ? sv[t + 1] : 0.f;
  float pw = GAMMA;
#pragma unroll
  for (int j = 63; j >= 0; --j) {
    G[t * 64 + j] = loc[j] + pw * nxt;
    pw *= GAMMA;
  }
}

// ------------------------------------------------------------ convert W ----
// W [k=1024][n=1024] fp32 -> BT [n=1024][k=1024] bf16 row-major (transpose+cvt)
__global__ __launch_bounds__(256) void convert_w(const float* __restrict__ W1,
                                                 const float* __restrict__ W2,
                                                 __bf16* __restrict__ BT1,
                                                 __bf16* __restrict__ BT2) {
  const int bx = blockIdx.x;
  const float* W = (bx >= 1024) ? W2 : W1;
  __bf16* O = (bx >= 1024) ? BT2 : BT1;
  const int tile = bx & 1023;
  const int ti = tile >> 5, tj = tile & 31;  // ti: k-tile, tj: n-tile
  __shared__ float s[32][33];
  const int t = threadIdx.x;
  const int rr = t >> 3, c4 = (t & 7) * 4;
  float4 v = *(const float4*)(W + (size_t)(ti * 32 + rr) * 1024 + tj * 32 + c4);
  s[rr][c4 + 0] = v.x; s[rr][c4 + 1] = v.y; s[rr][c4 + 2] = v.z; s[rr][c4 + 3] = v.w;
  __syncthreads();
  bf16x4 o = {(__bf16)s[c4 + 0][rr], (__bf16)s[c4 + 1][rr],
              (__bf16)s[c4 + 2][rr], (__bf16)s[c4 + 3][rr]};
  *(bf16x4*)(O + (size_t)(tj * 32 + rr) * 1024 + ti * 32 + c4) = o;
}

// ---------------------------------------------------------------------------
// Shared GEMM geometry: BM=BN=256, BK=64, 512 threads = 8 waves (2x4).
// LDS: A: [buf 2][half 2][16KB]  at 0      (swizzled: byte ^= (r&7)<<4)
//      B: [buf 2][half 2][16KB]  at 65536
// Phase p=(mh,nh): all 8 waves compute quadrant rows mh*128+, cols nh*128+.
// Wave (wsr=w>>2, wsc=w&3) owns 64x32 of the quadrant.
// ---------------------------------------------------------------------------

#define PHASE2(BC, MH, NH, STAGE_CODE, WAIT_CODE)                              \
  do {                                                                         \
    bf16x8 _a[4][2], _b[2][2];                                                 \
    _Pragma("unroll") for (int i = 0; i < 4; ++i) {                            \
      _a[i][0] = RDA(BC, MH, i, 0);                                            \
      _a[i][1] = RDA(BC, MH, i, 1);                                            \
    }                                                                          \
    _Pragma("unroll") for (int j = 0; j < 2; ++j) {                            \
      _b[j][0] = RDB(BC, NH, j, 0);                                            \
      _b[j][1] = RDB(BC, NH, j, 1);                                            \
    }                                                                          \
    STAGE_CODE;                                                                \
    WAIT_CODE;                                                                 \
    BAR();                                                                     \
    __builtin_amdgcn_s_setprio(1);                                             \
    _Pragma("unroll") for (int i = 0; i < 4; ++i)                              \
        _Pragma("unroll") for (int j = 0; j < 2; ++j) {                        \
      MFMA(acc[MH][i][NH][j], _a[i][0], _b[j][0]);                             \
      MFMA(acc[MH][i][NH][j], _a[i][1], _b[j][1]);                             \
    }                                                                          \
    __builtin_amdgcn_s_setprio(0);                                             \
    BAR();                                                                     \
  } while (0)

#define PHASE1(BC, MH, NH, STAGE_CODE, WAIT_CODE)                              \
  do {                                                                         \
    bf16x8 _a0[4], _b0[2];                                                     \
    _Pragma("unroll") for (int i = 0; i < 4; ++i) _a0[i] = RDA(BC, MH, i, 0);  \
    _Pragma("unroll") for (int j = 0; j < 2; ++j) _b0[j] = RDB(BC, NH, j, 0);  \
    STAGE_CODE;                                                                \
    WAIT_CODE;                                                                 \
    BAR();                                                                     \
    __builtin_amdgcn_s_setprio(1);                                             \
    _Pragma("unroll") for (int i = 0; i < 4; ++i)                              \
        _Pragma("unroll") for (int j = 0; j < 2; ++j)                          \
            MFMA(acc[MH][i][NH][j], _a0[i], _b0[j]);                           \
    bf16x8 _a1[4], _b1[2];                                                     \
    _Pragma("unroll") for (int i = 0; i < 4; ++i) _a1[i] = RDA(BC, MH, i, 1);  \
    _Pragma("unroll") for (int j = 0; j < 2; ++j) _b1[j] = RDB(BC, NH, j, 1);  \
    _Pragma("unroll") for (int i = 0; i < 4; ++i)                              \
        _Pragma("unroll") for (int j = 0; j < 2; ++j)                          \
            MFMA(acc[MH][i][NH][j], _a1[i], _b1[j]);                           \
    __builtin_amdgcn_s_setprio(0);                                             \
    BAR();                                                                     \
  } while (0)

// ---------------------------------------------------------------- GEMM1 ----
// h1 = relu(obs @ W1 + b1); A = obs fp32 (reg-staged + cvt), B = BT1 bf16.
__global__ __launch_bounds__(512, 2) void gemm1(const float* __restrict__ obs,
                                                const __bf16* __restrict__ BT1,
                                                const float* __restrict__ b1,
                                                __bf16* __restrict__ h1) {
  extern __shared__ char lds[];
  const int t = threadIdx.x, lane = t & 63, w = t >> 6;
  const int wsr = w >> 2, wsc = w & 3, g = lane >> 4, l15 = lane & 15;
  const int bid = blockIdx.x;
  const int mb = (bid & 7) * 32 + ((bid >> 3) >> 2);  // XCD-grouped
  const int nb = (bid >> 3) & 3;

  const int L = t * 16;
  const int rt = L >> 7;                          // 0..63
  const int koff = (L & 127) ^ ((rt & 7) << 4);   // swizzled byte-in-row (bf16)
  const char* Bb_g = (const char*)BT1 + (size_t)nb * 256 * 2048;
  const size_t boff = (size_t)rt * 2048 + koff;
  const char* Ab_g = (const char*)obs + (size_t)(mb * 256 + rt) * 4096 + koff * 2;

  f32x4 acc[2][4][2][2];
  const f32x4 zero = {0.f, 0.f, 0.f, 0.f};
#pragma unroll
  for (int a = 0; a < 2; ++a)
#pragma unroll
    for (int b = 0; b < 4; ++b)
#pragma unroll
      for (int c = 0; c < 2; ++c)
#pragma unroll
        for (int d = 0; d < 2; ++d) acc[a][b][c][d] = zero;

  auto STB = [&](int buf, int h, int kt) {
    const char* s = Bb_g + (size_t)h * 262144 + kt * 128 + boff;
    char* d = lds + 65536 + buf * 32768 + h * 16384 + L;
    gload_lds16(s, d);
    gload_lds16(s + 131072, d + 8192);
  };
  auto LDA4 = [&](int h, int kt, float4* av) {
    const char* s = Ab_g + (size_t)h * 524288 + kt * 256;
    av[0] = *(const float4*)(s);
    av[1] = *(const float4*)(s + 16);
    av[2] = *(const float4*)(s + 262144);
    av[3] = *(const float4*)(s + 262144 + 16);
  };
  auto WRA = [&](int buf, int h, const float4* av) {
    bf16x8 v0 = {(__bf16)av[0].x, (__bf16)av[0].y, (__bf16)av[0].z, (__bf16)av[0].w,
                 (__bf16)av[1].x, (__bf16)av[1].y, (__bf16)av[1].z, (__bf16)av[1].w};
    bf16x8 v1 = {(__bf16)av[2].x, (__bf16)av[2].y, (__bf16)av[2].z, (__bf16)av[2].w,
                 (__bf16)av[3].x, (__bf16)av[3].y, (__bf16)av[3].z, (__bf16)av[3].w};
    *(bf16x8*)(lds + buf * 32768 + h * 16384 + L) = v0;
    *(bf16x8*)(lds + buf * 32768 + h * 16384 + L + 8192) = v1;
  };
  auto RDA = [&](int buf, int mh, int i, int kk) -> bf16x8 {
    int r = wsr * 64 + 16 * i + l15;
    int b0 = r * 128 + kk * 64 + g * 16;
    return *(const bf16x8*)(lds + buf * 32768 + mh * 16384 + (b0 ^ ((r & 7) << 4)));
  };
  auto RDB = [&](int buf, int nh, int j, int kk) -> bf16x8 {
    int r = wsc * 32 + 16 * j + l15;
    int b0 = r * 128 + kk * 64 + g * 16;
    return *(const bf16x8*)(lds + 65536 + buf * 32768 + nh * 16384 +
                            (b0 ^ ((r & 7) << 4)));
  };

  float4 avA[4], avB[4];
  // prologue: tile 0 -> buf 0
  LDA4(0, 0, avA);
  LDA4(1, 0, avB);
  WRA(0, 0, avA);
  WRA(0, 1, avB);
  STB(0, 0, 0);
  STB(0, 1, 0);
  VMCNT(2);
  LGKM0();
  BAR();

  int cur = 0;
  for (int u = 0; u < 15; ++u) {
    const int nx = cur ^ 1, kn = u + 1;
    PHASE1(cur, 0, 0, { LDA4(0, kn, avA); }, { VMCNT(4); });
    PHASE1(cur, 0, 1, { LDA4(1, kn, avB); STB(nx, 0, kn); }, { ; });
    PHASE1(cur, 1, 0, { WRA(nx, 0, avA); STB(nx, 1, kn); }, { LGKM0(); });
    PHASE1(cur, 1, 1, { WRA(nx, 1, avB); }, { VMCNT(2); LGKM0(); });
    cur = nx;
  }
  PHASE1(cur, 0, 0, { ; }, { VMCNT(0); });
  PHASE1(cur, 0, 1, { ; }, { ; });
  PHASE1(cur, 1, 0, { ; }, { ; });
  PHASE1(cur, 1, 1, { ; }, { ; });

  // epilogue: relu(+b1) -> LDS tile [256][256] bf16 -> coalesced h1 store
  float b1v[2][2];
#pragma unroll
  for (int nh = 0; nh < 2; ++nh)
#pragma unroll
    for (int j = 0; j < 2; ++j)
      b1v[nh][j] = b1[nb * 256 + nh * 128 + wsc * 32 + 16 * j + l15];
  __bf16* ot = (__bf16*)lds;
#pragma unroll
  for (int mh = 0; mh < 2; ++mh)
#pragma unroll
    for (int i = 0; i < 4; ++i)
#pragma unroll
      for (int nh = 0; nh < 2; ++nh)
#pragma unroll
        for (int j = 0; j < 2; ++j)
#pragma unroll
          for (int reg = 0; reg < 4; ++reg) {
            float v = acc[mh][i][nh][j][reg] + b1v[nh][j];
            v = v > 0.f ? v : 0.f;
            const int Rl = mh * 128 + wsr * 64 + 16 * i + g * 4 + reg;
            const int Cl = nh * 128 + wsc * 32 + 16 * j + l15;
            ot[Rl * 256 + Cl] = (__bf16)v;
          }
  __syncthreads();
  {
    const int rr = t >> 1, seg = t & 1;
    const char* sp = lds + rr * 512 + seg * 256;
    char* dp = (char*)h1 + (size_t)(mb * 256 + rr) * 2048 + nb * 512 + seg * 256;
#pragma unroll
    for (int q = 0; q < 16; ++q)
      *(f32x4*)(dp + q * 16) = *(const f32x4*)(sp + q * 16);
  }
}

// ---------------------------------------------------------------- GEMM2 ----
// h2 = relu(h1 @ W2 + b2); fused V[m] += sum_c h2[m][c]*W3[c] (atomic, 4-way)
__global__ __launch_bounds__(512, 2) void gemm2(const __bf16* __restrict__ h1,
                                                const __bf16* __restrict__ BT2,
                                                const float* __restrict__ b2,
                                                const float* __restrict__ W3,
                                                float* __restrict__ V) {
  extern __shared__ char lds[];
  const int t = threadIdx.x, lane = t & 63, w = t >> 6;
  const int wsr = w >> 2, wsc = w & 3, g = lane >> 4, l15 = lane & 15;
  const int bid = blockIdx.x;
  const int mb = (bid & 7) * 32 + ((bid >> 3) >> 2);
  const int nb = (bid >> 3) & 3;

  const int L = t * 16;
  const int rt = L >> 7;
  const size_t aoff = (size_t)rt * 2048 + ((L & 127) ^ ((rt & 7) << 4));
  const char* Ab_g = (const char*)h1 + (size_t)mb * 256 * 2048;
  const char* Bb_g = (const char*)BT2 + (size_t)nb * 256 * 2048;

  f32x4 acc[2][4][2][2];
  const f32x4 zero = {0.f, 0.f, 0.f, 0.f};
#pragma unroll
  for (int a = 0; a < 2; ++a)
#pragma unroll
    for (int b = 0; b < 4; ++b)
#pragma unroll
      for (int c = 0; c < 2; ++c)
#pragma unroll
        for (int d = 0; d < 2; ++d) acc[a][b][c][d] = zero;

  auto STA = [&](int buf, int h, int kt) {
    const char* s = Ab_g + (size_t)h * 262144 + kt * 128 + aoff;
    char* d = lds + buf * 32768 + h * 16384 + L;
    gload_lds16(s, d);
    gload_lds16(s + 131072, d + 8192);
  };
  auto STB = [&](int buf, int h, int kt) {
    const char* s = Bb_g + (size_t)h * 262144 + kt * 128 + aoff;
    char* d = lds + 65536 + buf * 32768 + h * 16384 + L;
    gload_lds16(s, d);
    gload_lds16(s + 131072, d + 8192);
  };
  auto RDA = [&](int buf, int mh, int i, int kk) -> bf16x8 {
    int r = wsr * 64 + 16 * i + l15;
    int b0 = r * 128 + kk * 64 + g * 16;
    return *(const bf16x8*)(lds + buf * 32768 + mh * 16384 + (b0 ^ ((r & 7) << 4)));
  };
  auto RDB = [&](int buf, int nh, int j, int kk) -> bf16x8 {
    int r = wsc * 32 + 16 * j + l15;
    int b0 = r * 128 + kk * 64 + g * 16;
    return *(const bf16x8*)(lds + 65536 + buf * 32768 + nh * 16384 +
                            (b0 ^ ((r & 7) << 4)));
  };

  // prologue: tile 0 -> buf 0  (order: A0, B0, B1, A1)
  STA(0, 0, 0);
  STB(0, 0, 0);
  STB(0, 1, 0);
  STA(0, 1, 0);
  VMCNT(4);
  BAR();

  int cur = 0;
  for (int u = 0; u < 15; ++u) {
    const int nx = cur ^ 1, kn = u + 1;
    PHASE2(cur, 0, 0, { STA(nx, 0, kn); }, { VMCNT(4); });
    PHASE2(cur, 0, 1, { STB(nx, 0, kn); }, { VMCNT(4); });
    PHASE2(cur, 1, 0, { STB(nx, 1, kn); }, { ; });
    PHASE2(cur, 1, 1, { STA(nx, 1, kn); }, { VMCNT(4); });
    cur = nx;
  }
  PHASE2(cur, 0, 0, { ; }, { VMCNT(2); });
  PHASE2(cur, 0, 1, { ; }, { VMCNT(0); });
  PHASE2(cur, 1, 0, { ; }, { ; });
  PHASE2(cur, 1, 1, { ; }, { ; });

  // epilogue: p[row] = sum_cols relu(acc + b2)*W3 ; 16-lane reduce; LDS; atomic
  float b2v[2][2], w3v[2][2];
#pragma unroll
  for (int nh = 0; nh < 2; ++nh)
#pragma unroll
    for (int j = 0; j < 2; ++j) {
      const int C = nb * 256 + nh * 128 + wsc * 32 + 16 * j + l15;
      b2v[nh][j] = b2[C];
      w3v[nh][j] = W3[C];
    }
  float p[2][4][4];
#pragma unroll
  for (int mh = 0; mh < 2; ++mh)
#pragma unroll
    for (int i = 0; i < 4; ++i)
#pragma unroll
      for (int reg = 0; reg < 4; ++reg) {
        float s = 0.f;
#pragma unroll
        for (int nh = 0; nh < 2; ++nh)
#pragma unroll
          for (int j = 0; j < 2; ++j) {
            float v = acc[mh][i][nh][j][reg] + b2v[nh][j];
            v = v > 0.f ? v : 0.f;
            s += v * w3v[nh][j];
          }
        p[mh][i][reg] = s;
      }
#pragma unroll
  for (int d = 1; d < 16; d <<= 1)
#pragma unroll
    for (int mh = 0; mh < 2; ++mh)
#pragma unroll
      for (int i = 0; i < 4; ++i)
#pragma unroll
        for (int reg = 0; reg < 4; ++reg)
          p[mh][i][reg] += __shfl_xor(p[mh][i][reg], d, 64);
  float* vp = (float*)lds;  // [4 wsc][256 rows]
  if (l15 == 0) {
#pragma unroll
    for (int mh = 0; mh < 2; ++mh)
#pragma unroll
      for (int i = 0; i < 4; ++i)
#pragma unroll
        for (int reg = 0; reg < 4; ++reg)
          vp[wsc * 256 + mh * 128 + wsr * 64 + 16 * i + g * 4 + reg] = p[mh][i][reg];
  }
  __syncthreads();
  if (t < 256) {
    float s = vp[t] + vp[256 + t] + vp[512 + t] + vp[768 + t];
    atomicAdd(&V[mb * 256 + t], s);
  }
}

// ---------------------------------------------------------------- final ----
__global__ __launch_bounds__(256) void final_kernel(const float* __restrict__ G,
                                                    const float* __restrict__ V,
                                                    const float* __restrict__ b3,
                                                    float* __restrict__ out) {
  int i = blockIdx.x * 256 + threadIdx.x;
  out[i] = G[i] - (V[i] + b3[0]);
}

extern "C" void kernel_launch(void* const* d_in, const int* in_sizes, int n_in,
                              void* d_out, int out_size, void* d_ws, size_t ws_size,
                              hipStream_t stream) {
  const float* rewards = (const float*)d_in[0];
  const float* obs = (const float*)d_in[1];
  const float* W1 = (const float*)d_in[2];
  const float* b1 = (const float*)d_in[3];
  const float* W2 = (const float*)d_in[4];
  const float* b2 = (const float*)d_in[5];
  const float* W3 = (const float*)d_in[6];
  const float* b3 = (const float*)d_in[7];
  float* out = (float*)d_out;

  char* ws = (char*)d_ws;
  __bf16* BT1 = (__bf16*)(ws);                          // 2 MiB
  __bf16* BT2 = (__bf16*)(ws + (2u << 20));             // 2 MiB
  float* V = (float*)(ws + (4u << 20));                 // 256 KiB
  float* G = (float*)(ws + (4u << 20) + (256u << 10));  // 256 KiB
  __bf16* h1 = (__bf16*)(ws + (8u << 20));              // 128 MiB

  hipFuncSetAttribute((const void*)gemm1, hipFuncAttributeMaxDynamicSharedMemorySize,
                      131072);
  hipFuncSetAttribute((const void*)gemm2, hipFuncAttributeMaxDynamicSharedMemorySize,
                      131072);

  scan_kernel<<<1, 1024, 0, stream>>>(rewards, G);
  convert_w<<<2048, 256, 0, stream>>>(W1, W2, BT1, BT2);
  gemm1<<<1024, 512, 131072, stream>>>(obs, BT1, b1, h1);
  hipMemsetAsync(V, 0, 65536 * sizeof(float), stream);
  gemm2<<<1024, 512, 131072, stream>>>(h1, BT2, b2, W3, V);
  final_kernel<<<256, 256, 0, stream>>>(G, V, b3, out);
}

// Round 4
// 380.634 us; speedup vs baseline: 1.4478x; 1.1585x over previous
//
#include <hip/hip_runtime.h>

typedef __bf16 bf16x8 __attribute__((ext_vector_type(8)));
typedef __bf16 bf16x4 __attribute__((ext_vector_type(4)));
typedef float  f32x4  __attribute__((ext_vector_type(4)));

#define GAMMA 0.99f

__device__ __forceinline__ void gload_lds16(const void* g, void* l) {
  __builtin_amdgcn_global_load_lds(
      (const __attribute__((address_space(1))) void*)g,
      (__attribute__((address_space(3))) void*)l, 16, 0, 0);
}

#define VMCNT(n) asm volatile("s_waitcnt vmcnt(" #n ")" ::: "memory")
#define LGKM0()                                         \
  do {                                                  \
    asm volatile("s_waitcnt lgkmcnt(0)" ::: "memory");  \
    __builtin_amdgcn_sched_barrier(0);                  \
  } while (0)
#define BAR() __builtin_amdgcn_s_barrier()
#define MFMA(d, a, b) d = __builtin_amdgcn_mfma_f32_16x16x32_bf16(a, b, d, 0, 0, 0)

// ------------------------------------------------- mega: scan + converts ----
// block 0            : discounted-return scan (1024 threads)
// blocks 1..nObs     : obs fp32 -> bf16 streaming convert
// blocks nObs+1..+512: W1/W2 transpose+cvt -> BT1/BT2 (4 subtiles per block)
__global__ __launch_bounds__(1024) void mega_prep(
    const float* __restrict__ rw, float* __restrict__ G,
    const float* __restrict__ obs, __bf16* __restrict__ obsb,
    const float* __restrict__ W1, const float* __restrict__ W2,
    __bf16* __restrict__ BT1, __bf16* __restrict__ BT2, int nObs) {
  __shared__ float smem[4224];
  const int blk = blockIdx.x;
  const int t = threadIdx.x;
  if (blk == 0) {
    // ---- scan ----
    float* sv = smem;
    const float4* rp = (const float4*)(rw + t * 64);
    float4 lv[16];
#pragma unroll
    for (int i = 0; i < 16; ++i) lv[i] = rp[i];
    float loc[64];
#pragma unroll
    for (int i = 0; i < 16; ++i) {
      loc[4 * i + 0] = lv[i].x; loc[4 * i + 1] = lv[i].y;
      loc[4 * i + 2] = lv[i].z; loc[4 * i + 3] = lv[i].w;
    }
    float g = 0.f;
#pragma unroll
    for (int j = 63; j >= 0; --j) { g = loc[j] + GAMMA * g; loc[j] = g; }
    sv[t] = g;
    float W = GAMMA;
#pragma unroll
    for (int i = 0; i < 6; ++i) W *= W;  // gamma^64
    float v = g;
    for (int s = 1; s < 1024; s <<= 1) {
      __syncthreads();
      float o = (t + s < 1024) ? sv[t + s] : 0.f;
      __syncthreads();
      v += W * o;
      sv[t] = v;
      W *= W;
    }
    __syncthreads();
    const float nxt = (t < 1023) ? sv[t + 1] : 0.f;
    float pw = GAMMA;
#pragma unroll
    for (int j = 63; j >= 0; --j) {
      G[t * 64 + j] = loc[j] + pw * nxt;
      pw *= GAMMA;
    }
  } else if (blk <= nObs) {
    // ---- obs convert: 32768 elems per block ----
    const size_t base = (size_t)(blk - 1) * 32768 + (size_t)t * 8;
#pragma unroll
    for (int it = 0; it < 4; ++it) {
      const size_t e = base + (size_t)it * 8192;
      float4 u0 = *(const float4*)(obs + e);
      float4 u1 = *(const float4*)(obs + e + 4);
      bf16x8 o = {(__bf16)u0.x, (__bf16)u0.y, (__bf16)u0.z, (__bf16)u0.w,
                  (__bf16)u1.x, (__bf16)u1.y, (__bf16)u1.z, (__bf16)u1.w};
      *(bf16x8*)(obsb + e) = o;
    }
  } else {
    // ---- W transpose+cvt: 4 subtiles of 32x32 per block ----
    const int sub = t >> 8, tt = t & 255;
    const int wi = (blk - nObs - 1) * 4 + sub;  // 0..2047
    const float* W = (wi >= 1024) ? W2 : W1;
    __bf16* O = (wi >= 1024) ? BT2 : BT1;
    const int tile = wi & 1023;
    const int ti = tile >> 5, tj = tile & 31;
    float* s = smem + sub * 1056;  // [32][33]
    const int rr = tt >> 3, c4 = (tt & 7) * 4;
    float4 v = *(const float4*)(W + (size_t)(ti * 32 + rr) * 1024 + tj * 32 + c4);
    s[rr * 33 + c4 + 0] = v.x; s[rr * 33 + c4 + 1] = v.y;
    s[rr * 33 + c4 + 2] = v.z; s[rr * 33 + c4 + 3] = v.w;
    __syncthreads();
    bf16x4 o = {(__bf16)s[(c4 + 0) * 33 + rr], (__bf16)s[(c4 + 1) * 33 + rr],
                (__bf16)s[(c4 + 2) * 33 + rr], (__bf16)s[(c4 + 3) * 33 + rr]};
    *(bf16x4*)(O + (size_t)(tj * 32 + rr) * 1024 + ti * 32 + c4) = o;
  }
}

// ---------------------------------------------------------------------------
// GEMM geometry: BM=BN=256, BK=64, 512 threads = 8 waves (2x4).
// LDS: A: [buf 2][half 2][16KB] at 0 ; B: same at 65536. Swizzle ^= (r&7)<<4.
// ---------------------------------------------------------------------------

#define PHASE2(BC, MH, NH, STAGE_CODE, WAIT_CODE)                              \
  do {                                                                         \
    bf16x8 _a[4][2], _b[2][2];                                                 \
    _Pragma("unroll") for (int i = 0; i < 4; ++i) {                            \
      _a[i][0] = RDA(BC, MH, i, 0);                                            \
      _a[i][1] = RDA(BC, MH, i, 1);                                            \
    }                                                                          \
    _Pragma("unroll") for (int j = 0; j < 2; ++j) {                            \
      _b[j][0] = RDB(BC, NH, j, 0);                                            \
      _b[j][1] = RDB(BC, NH, j, 1);                                            \
    }                                                                          \
    STAGE_CODE;                                                                \
    WAIT_CODE;                                                                 \
    BAR();                                                                     \
    __builtin_amdgcn_s_setprio(1);                                             \
    _Pragma("unroll") for (int i = 0; i < 4; ++i)                              \
        _Pragma("unroll") for (int j = 0; j < 2; ++j) {                        \
      MFMA(acc[MH][i][NH][j], _a[i][0], _b[j][0]);                             \
      MFMA(acc[MH][i][NH][j], _a[i][1], _b[j][1]);                             \
    }                                                                          \
    __builtin_amdgcn_s_setprio(0);                                             \
    BAR();                                                                     \
  } while (0)

#define GEMM_COMMON(APTR, BPTR)                                                \
  extern __shared__ char lds[];                                                \
  const int t = threadIdx.x, lane = t & 63, w = t >> 6;                        \
  const int wsr = w >> 2, wsc = w & 3, g = lane >> 4, l15 = lane & 15;         \
  const int bid = blockIdx.x;                                                  \
  const int mb = (bid & 7) * 32 + ((bid >> 3) >> 2);                           \
  const int nb = (bid >> 3) & 3;                                               \
  const int L = t * 16;                                                        \
  const int rt = L >> 7;                                                       \
  const size_t aoff = (size_t)rt * 2048 + ((L & 127) ^ ((rt & 7) << 4));       \
  const char* Ab_g = (const char*)(APTR) + (size_t)mb * 256 * 2048;            \
  const char* Bb_g = (const char*)(BPTR) + (size_t)nb * 256 * 2048;            \
  f32x4 acc[2][4][2][2];                                                       \
  const f32x4 zero = {0.f, 0.f, 0.f, 0.f};                                     \
  _Pragma("unroll") for (int a = 0; a < 2; ++a)                                \
      _Pragma("unroll") for (int b = 0; b < 4; ++b)                            \
          _Pragma("unroll") for (int c = 0; c < 2; ++c)                        \
              _Pragma("unroll") for (int d = 0; d < 2; ++d)                    \
                  acc[a][b][c][d] = zero;                                      \
  auto STA = [&](int buf, int h, int kt) {                                     \
    const char* s = Ab_g + (size_t)h * 262144 + kt * 128 + aoff;               \
    char* d = lds + buf * 32768 + h * 16384 + L;                               \
    gload_lds16(s, d);                                                         \
    gload_lds16(s + 131072, d + 8192);                                         \
  };                                                                           \
  auto STB = [&](int buf, int h, int kt) {                                     \
    const char* s = Bb_g + (size_t)h * 262144 + kt * 128 + aoff;               \
    char* d = lds + 65536 + buf * 32768 + h * 16384 + L;                       \
    gload_lds16(s, d);                                                         \
    gload_lds16(s + 131072, d + 8192);                                         \
  };                                                                           \
  auto RDA = [&](int buf, int mh, int i, int kk) -> bf16x8 {                   \
    int r = wsr * 64 + 16 * i + l15;                                           \
    int b0 = r * 128 + kk * 64 + g * 16;                                       \
    return *(const bf16x8*)(lds + buf * 32768 + mh * 16384 +                   \
                            (b0 ^ ((r & 7) << 4)));                            \
  };                                                                           \
  auto RDB = [&](int buf, int nh, int j, int kk) -> bf16x8 {                   \
    int r = wsc * 32 + 16 * j + l15;                                           \
    int b0 = r * 128 + kk * 64 + g * 16;                                       \
    return *(const bf16x8*)(lds + 65536 + buf * 32768 + nh * 16384 +           \
                            (b0 ^ ((r & 7) << 4)));                            \
  };                                                                           \
  STA(0, 0, 0);                                                                \
  STB(0, 0, 0);                                                                \
  STB(0, 1, 0);                                                                \
  STA(0, 1, 0);                                                                \
  VMCNT(4);                                                                    \
  BAR();                                                                       \
  int cur = 0;                                                                 \
  for (int u = 0; u < 15; ++u) {                                               \
    const int nx = cur ^ 1, kn = u + 1;                                        \
    PHASE2(cur, 0, 0, { STA(nx, 0, kn); }, { VMCNT(4); });                     \
    PHASE2(cur, 0, 1, { STB(nx, 0, kn); }, { VMCNT(4); });                     \
    PHASE2(cur, 1, 0, { STB(nx, 1, kn); }, { ; });                             \
    PHASE2(cur, 1, 1, { STA(nx, 1, kn); }, { VMCNT(4); });                     \
    cur = nx;                                                                  \
  }                                                                            \
  PHASE2(cur, 0, 0, { ; }, { VMCNT(2); });                                     \
  PHASE2(cur, 0, 1, { ; }, { VMCNT(0); });                                     \
  PHASE2(cur, 1, 0, { ; }, { ; });                                             \
  PHASE2(cur, 1, 1, { ; }, { ; });

// ---------------------------------------------------------------- GEMM1 ----
// h1 = relu(obs_bf16 @ W1 + b1); pure gload_lds both operands.
__global__ __launch_bounds__(512, 2) void gemm1_bf16(
    const __bf16* __restrict__ obsb, const __bf16* __restrict__ BT1,
    const float* __restrict__ b1, __bf16* __restrict__ h1) {
  GEMM_COMMON(obsb, BT1)
  // epilogue: relu(+b1) -> LDS [256][256] bf16 -> coalesced h1 store
  float b1v[2][2];
#pragma unroll
  for (int nh = 0; nh < 2; ++nh)
#pragma unroll
    for (int j = 0; j < 2; ++j)
      b1v[nh][j] = b1[nb * 256 + nh * 128 + wsc * 32 + 16 * j + l15];
  __bf16* ot = (__bf16*)lds;
#pragma unroll
  for (int mh = 0; mh < 2; ++mh)
#pragma unroll
    for (int i = 0; i < 4; ++i)
#pragma unroll
      for (int nh = 0; nh < 2; ++nh)
#pragma unroll
        for (int j = 0; j < 2; ++j)
#pragma unroll
          for (int reg = 0; reg < 4; ++reg) {
            float v = acc[mh][i][nh][j][reg] + b1v[nh][j];
            v = v > 0.f ? v : 0.f;
            const int Rl = mh * 128 + wsr * 64 + 16 * i + g * 4 + reg;
            const int Cl = nh * 128 + wsc * 32 + 16 * j + l15;
            ot[Rl * 256 + Cl] = (__bf16)v;
          }
  __syncthreads();
  {
    const int rr = t >> 1, seg = t & 1;
    const char* sp = lds + rr * 512 + seg * 256;
    char* dp = (char*)h1 + (size_t)(mb * 256 + rr) * 2048 + nb * 512 + seg * 256;
#pragma unroll
    for (int q = 0; q < 16; ++q)
      *(f32x4*)(dp + q * 16) = *(const f32x4*)(sp + q * 16);
  }
}

// ------------------------------------------------- GEMM1 fallback (fp32) ----
#define PHASE1(BC, MH, NH, STAGE_CODE, WAIT_CODE)                              \
  do {                                                                         \
    bf16x8 _a0[4], _b0[2];                                                     \
    _Pragma("unroll") for (int i = 0; i < 4; ++i) _a0[i] = RDA(BC, MH, i, 0);  \
    _Pragma("unroll") for (int j = 0; j < 2; ++j) _b0[j] = RDB(BC, NH, j, 0);  \
    STAGE_CODE;                                                                \
    WAIT_CODE;                                                                 \
    BAR();                                                                     \
    __builtin_amdgcn_s_setprio(1);                                             \
    _Pragma("unroll") for (int i = 0; i < 4; ++i)                              \
        _Pragma("unroll") for (int j = 0; j < 2; ++j)                          \
            MFMA(acc[MH][i][NH][j], _a0[i], _b0[j]);                           \
    bf16x8 _a1[4], _b1[2];                                                     \
    _Pragma("unroll") for (int i = 0; i < 4; ++i) _a1[i] = RDA(BC, MH, i, 1);  \
    _Pragma("unroll") for (int j = 0; j < 2; ++j) _b1[j] = RDB(BC, NH, j, 1);  \
    _Pragma("unroll") for (int i = 0; i < 4; ++i)                              \
        _Pragma("unroll") for (int j = 0; j < 2; ++j)                          \
            MFMA(acc[MH][i][NH][j], _a1[i], _b1[j]);                           \
    __builtin_amdgcn_s_setprio(0);                                             \
    BAR();                                                                     \
  } while (0)

__global__ __launch_bounds__(512, 2) void gemm1_fp32(
    const float* __restrict__ obs, const __bf16* __restrict__ BT1,
    const float* __restrict__ b1, __bf16* __restrict__ h1) {
  extern __shared__ char lds[];
  const int t = threadIdx.x, lane = t & 63, w = t >> 6;
  const int wsr = w >> 2, wsc = w & 3, g = lane >> 4, l15 = lane & 15;
  const int bid = blockIdx.x;
  const int mb = (bid & 7) * 32 + ((bid >> 3) >> 2);
  const int nb = (bid >> 3) & 3;
  const int L = t * 16;
  const int rt = L >> 7;
  const int koff = (L & 127) ^ ((rt & 7) << 4);
  const char* Bb_g = (const char*)BT1 + (size_t)nb * 256 * 2048;
  const size_t boff = (size_t)rt * 2048 + koff;
  const char* Ab_g = (const char*)obs + (size_t)(mb * 256 + rt) * 4096 + koff * 2;
  f32x4 acc[2][4][2][2];
  const f32x4 zero = {0.f, 0.f, 0.f, 0.f};
#pragma unroll
  for (int a = 0; a < 2; ++a)
#pragma unroll
    for (int b = 0; b < 4; ++b)
#pragma unroll
      for (int c = 0; c < 2; ++c)
#pragma unroll
        for (int d = 0; d < 2; ++d) acc[a][b][c][d] = zero;
  auto STB = [&](int buf, int h, int kt) {
    const char* s = Bb_g + (size_t)h * 262144 + kt * 128 + boff;
    char* d = lds + 65536 + buf * 32768 + h * 16384 + L;
    gload_lds16(s, d);
    gload_lds16(s + 131072, d + 8192);
  };
  auto LDA4 = [&](int h, int kt, float4* av) {
    const char* s = Ab_g + (size_t)h * 524288 + kt * 256;
    av[0] = *(const float4*)(s);
    av[1] = *(const float4*)(s + 16);
    av[2] = *(const float4*)(s + 262144);
    av[3] = *(const float4*)(s + 262144 + 16);
  };
  auto WRA = [&](int buf, int h, const float4* av) {
    bf16x8 v0 = {(__bf16)av[0].x, (__bf16)av[0].y, (__bf16)av[0].z, (__bf16)av[0].w,
                 (__bf16)av[1].x, (__bf16)av[1].y, (__bf16)av[1].z, (__bf16)av[1].w};
    bf16x8 v1 = {(__bf16)av[2].x, (__bf16)av[2].y, (__bf16)av[2].z, (__bf16)av[2].w,
                 (__bf16)av[3].x, (__bf16)av[3].y, (__bf16)av[3].z, (__bf16)av[3].w};
    *(bf16x8*)(lds + buf * 32768 + h * 16384 + L) = v0;
    *(bf16x8*)(lds + buf * 32768 + h * 16384 + L + 8192) = v1;
  };
  auto RDA = [&](int buf, int mh, int i, int kk) -> bf16x8 {
    int r = wsr * 64 + 16 * i + l15;
    int b0 = r * 128 + kk * 64 + g * 16;
    return *(const bf16x8*)(lds + buf * 32768 + mh * 16384 + (b0 ^ ((r & 7) << 4)));
  };
  auto RDB = [&](int buf, int nh, int j, int kk) -> bf16x8 {
    int r = wsc * 32 + 16 * j + l15;
    int b0 = r * 128 + kk * 64 + g * 16;
    return *(const bf16x8*)(lds + 65536 + buf * 32768 + nh * 16384 +
                            (b0 ^ ((r & 7) << 4)));
  };
  float4 avA[4], avB[4];
  LDA4(0, 0, avA);
  LDA4(1, 0, avB);
  WRA(0, 0, avA);
  WRA(0, 1, avB);
  STB(0, 0, 0);
  STB(0, 1, 0);
  VMCNT(2);
  LGKM0();
  BAR();
  int cur = 0;
  for (int u = 0; u < 15; ++u) {
    const int nx = cur ^ 1, kn = u + 1;
    PHASE1(cur, 0, 0, { LDA4(0, kn, avA); }, { VMCNT(4); });
    PHASE1(cur, 0, 1, { LDA4(1, kn, avB); STB(nx, 0, kn); }, { ; });
    PHASE1(cur, 1, 0, { WRA(nx, 0, avA); STB(nx, 1, kn); }, { LGKM0(); });
    PHASE1(cur, 1, 1, { WRA(nx, 1, avB); }, { VMCNT(2); LGKM0(); });
    cur = nx;
  }
  PHASE1(cur, 0, 0, { ; }, { VMCNT(0); });
  PHASE1(cur, 0, 1, { ; }, { ; });
  PHASE1(cur, 1, 0, { ; }, { ; });
  PHASE1(cur, 1, 1, { ; }, { ; });
  float b1v[2][2];
#pragma unroll
  for (int nh = 0; nh < 2; ++nh)
#pragma unroll
    for (int j = 0; j < 2; ++j)
      b1v[nh][j] = b1[nb * 256 + nh * 128 + wsc * 32 + 16 * j + l15];
  __bf16* ot = (__bf16*)lds;
#pragma unroll
  for (int mh = 0; mh < 2; ++mh)
#pragma unroll
    for (int i = 0; i < 4; ++i)
#pragma unroll
      for (int nh = 0; nh < 2; ++nh)
#pragma unroll
        for (int j = 0; j < 2; ++j)
#pragma unroll
          for (int reg = 0; reg < 4; ++reg) {
            float v = acc[mh][i][nh][j][reg] + b1v[nh][j];
            v = v > 0.f ? v : 0.f;
            const int Rl = mh * 128 + wsr * 64 + 16 * i + g * 4 + reg;
            const int Cl = nh * 128 + wsc * 32 + 16 * j + l15;
            ot[Rl * 256 + Cl] = (__bf16)v;
          }
  __syncthreads();
  {
    const int rr = t >> 1, seg = t & 1;
    const char* sp = lds + rr * 512 + seg * 256;
    char* dp = (char*)h1 + (size_t)(mb * 256 + rr) * 2048 + nb * 512 + seg * 256;
#pragma unroll
    for (int q = 0; q < 16; ++q)
      *(f32x4*)(dp + q * 16) = *(const f32x4*)(sp + q * 16);
  }
}

// ---------------------------------------------------------------- GEMM2 ----
// h2 = relu(h1 @ W2 + b2); fused V4[nb][m] = sum_c h2[m][c]*W3[c] (no atomics)
__global__ __launch_bounds__(512, 2) void gemm2(const __bf16* __restrict__ h1,
                                                const __bf16* __restrict__ BT2,
                                                const float* __restrict__ b2,
                                                const float* __restrict__ W3,
                                                float* __restrict__ V4) {
  GEMM_COMMON(h1, BT2)
  // epilogue: p[row] = sum_cols relu(acc+b2)*W3; 16-lane reduce; direct store
  float b2v[2][2], w3v[2][2];
#pragma unroll
  for (int nh = 0; nh < 2; ++nh)
#pragma unroll
    for (int j = 0; j < 2; ++j) {
      const int C = nb * 256 + nh * 128 + wsc * 32 + 16 * j + l15;
      b2v[nh][j] = b2[C];
      w3v[nh][j] = W3[C];
    }
  float p[2][4][4];
#pragma unroll
  for (int mh = 0; mh < 2; ++mh)
#pragma unroll
    for (int i = 0; i < 4; ++i)
#pragma unroll
      for (int reg = 0; reg < 4; ++reg) {
        float s = 0.f;
#pragma unroll
        for (int nh = 0; nh < 2; ++nh)
#pragma unroll
          for (int j = 0; j < 2; ++j) {
            float v = acc[mh][i][nh][j][reg] + b2v[nh][j];
            v = v > 0.f ? v : 0.f;
            s += v * w3v[nh][j];
          }
        p[mh][i][reg] = s;
      }
#pragma unroll
  for (int d = 1; d < 16; d <<= 1)
#pragma unroll
    for (int mh = 0; mh < 2; ++mh)
#pragma unroll
      for (int i = 0; i < 4; ++i)
#pragma unroll
        for (int reg = 0; reg < 4; ++reg)
          p[mh][i][reg] += __shfl_xor(p[mh][i][reg], d, 64);
  float* vp = (float*)lds;  // [4 wsc][256 rows]
  if (l15 == 0) {
#pragma unroll
    for (int mh = 0; mh < 2; ++mh)
#pragma unroll
      for (int i = 0; i < 4; ++i)
#pragma unroll
        for (int reg = 0; reg < 4; ++reg)
          vp[wsc * 256 + mh * 128 + wsr * 64 + 16 * i + g * 4 + reg] = p[mh][i][reg];
  }
  __syncthreads();
  if (t < 256) {
    float s = vp[t] + vp[256 + t] + vp[512 + t] + vp[768 + t];
    V4[(size_t)nb * 65536 + mb * 256 + t] = s;
  }
}

// ---------------------------------------------------------------- final ----
__global__ __launch_bounds__(256) void final_kernel(const float* __restrict__ G,
                                                    const float* __restrict__ V4,
                                                    const float* __restrict__ b3,
                                                    float* __restrict__ out) {
  int i = blockIdx.x * 256 + threadIdx.x;
  out[i] = G[i] - (V4[i] + V4[65536 + i] + V4[131072 + i] + V4[196608 + i] + b3[0]);
}

extern "C" void kernel_launch(void* const* d_in, const int* in_sizes, int n_in,
                              void* d_out, int out_size, void* d_ws, size_t ws_size,
                              hipStream_t stream) {
  const float* rewards = (const float*)d_in[0];
  const float* obs = (const float*)d_in[1];
  const float* W1 = (const float*)d_in[2];
  const float* b1 = (const float*)d_in[3];
  const float* W2 = (const float*)d_in[4];
  const float* b2 = (const float*)d_in[5];
  const float* W3 = (const float*)d_in[6];
  const float* b3 = (const float*)d_in[7];
  float* out = (float*)d_out;

  char* ws = (char*)d_ws;
  __bf16* BT1 = (__bf16*)(ws);                 // 2 MiB
  __bf16* BT2 = (__bf16*)(ws + (2u << 20));    // 2 MiB
  float* V4 = (float*)(ws + (4u << 20));       // 1 MiB
  float* G = (float*)(ws + (5u << 20));        // 256 KiB
  const bool big = ws_size >= (size_t)(266u) * (1u << 20);
  __bf16* obsb = (__bf16*)(ws + (8u << 20));            // 128 MiB (big only)
  __bf16* h1 = big ? (__bf16*)(ws + (136u << 20))       // 128 MiB
                   : (__bf16*)(ws + (8u << 20));

  hipFuncSetAttribute((const void*)gemm1_bf16,
                      hipFuncAttributeMaxDynamicSharedMemorySize, 131072);
  hipFuncSetAttribute((const void*)gemm1_fp32,
                      hipFuncAttributeMaxDynamicSharedMemorySize, 131072);
  hipFuncSetAttribute((const void*)gemm2,
                      hipFuncAttributeMaxDynamicSharedMemorySize, 131072);

  const int nObs = big ? 2048 : 0;
  mega_prep<<<1 + nObs + 512, 1024, 0, stream>>>(rewards, G, obs, obsb, W1, W2,
                                                 BT1, BT2, nObs);
  if (big)
    gemm1_bf16<<<1024, 512, 131072, stream>>>(obsb, BT1, b1, h1);
  else
    gemm1_fp32<<<1024, 512, 131072, stream>>>(obs, BT1, b1, h1);
  gemm2<<<1024, 512, 131072, stream>>>(h1, BT2, b2, W3, V4);
  final_kernel<<<256, 256, 0, stream>>>(G, V4, b3, out);
}